// Round 7
// baseline (220.055 us; speedup 1.0000x reference)
//
#include <hip/hip_runtime.h>
#include <hip/hip_fp16.h>

constexpr int EMB = 512;
constexpr int NXCD = 8;                          // pair_acc replicas (XCD-partitioned)

typedef float floatx4 __attribute__((ext_vector_type(4)));  // native vec for nontemporal

// ---- 32-bit packed (count,sum) for pair accumulation ----
// a = cnt*2^26 + round(t*2^20); |t|<=0.35, cnt<=~24 -> |qsum|<2^24, cnt<64.
// Fields add linearly, so replica sums combine by plain u32 addition.
constexpr float T_SCALE = 1048576.0f;            // 2^20
constexpr float T_INV_SCALE = 1.0f / 1048576.0f;

__device__ __forceinline__ unsigned pack1_32(float t) {
    int q = __float2int_rn(t * T_SCALE);
    return (unsigned)(q + (1 << 26));
}
__device__ __forceinline__ void unpack32(unsigned a, int& cnt, float& sum) {
    cnt = (int)((a + (1u << 25)) >> 26);
    int q = (int)(a - ((unsigned)cnt << 26));
    sum = (float)q * T_INV_SCALE;
}

// ---- 64-bit packed (count,sum) for place accumulation ----
constexpr float FP_SCALE = 4194304.0f;           // 2^22
constexpr float FP_INV_SCALE = 1.0f / 4194304.0f;

__device__ __forceinline__ unsigned long long pack1_64(float v) {
    long long q = (long long)__float2int_rn(v * FP_SCALE);
    return (unsigned long long)(q + (1LL << 32));
}
__device__ __forceinline__ void unpack64(unsigned long long p, int& cnt, float& sum) {
    long long t = (long long)p;
    cnt = (int)((t + (1LL << 31)) >> 32);
    long long q = t - ((long long)cnt << 32);
    sum = (float)q * FP_INV_SCALE;
}

// One wave (64 lanes) per node row: 128 float4 per row -> 2 float4/lane.
// Writes f32 table (pair_k accuracy) + fp16 table (32 KB, for event gathers).
__global__ void node_mean_k(const float* __restrict__ emb,
                            float* __restrict__ node_mean,
                            __half* __restrict__ node_mean16, int n_nodes) {
    int gwave = (blockIdx.x * blockDim.x + threadIdx.x) >> 6;
    int lane = threadIdx.x & 63;
    if (gwave >= n_nodes) return;
    const float4* row = (const float4*)emb + (size_t)gwave * (EMB / 4);
    float4 a = row[lane];
    float4 b = row[lane + 64];
    float s = (a.x + a.y) + (a.z + a.w) + (b.x + b.y) + (b.z + b.w);
#pragma unroll
    for (int off = 32; off > 0; off >>= 1)
        s += __shfl_down(s, off, 64);
    if (lane == 0) {
        float m = s * (1.0f / (float)EMB);
        node_mean[gwave] = m;
        node_mean16[gwave] = __float2half(m);
    }
}

// dst_event sorted (repeat(arange, ndst)), segments of length 1..4.
// Segment-start thread: speculative parallel loads of the next 3 entries
// (no serial dependent walk), all nm16 gathers issued together, one packed
// u32 atomic into the XCD-local pair_acc replica (blockIdx&7) — keeps atomic
// lines resident in one XCD's L2 instead of bouncing through HBM.
__global__ void event_fused_k(const int* __restrict__ dst_event,
                              const int* __restrict__ dst_node,
                              const int* __restrict__ event_pair,
                              const int* __restrict__ event_src,
                              const __half* __restrict__ nm16,
                              unsigned* __restrict__ pair_acc,
                              int n_dst, int n_pairs) {
    int i = blockIdx.x * blockDim.x + threadIdx.x;
    if (i >= n_dst) return;
    int e = __builtin_nontemporal_load(dst_event + i);
    if (i > 0 && __builtin_nontemporal_load(dst_event + i - 1) == e) return;

    int last = n_dst - 1;
    int i1 = min(i + 1, last), i2 = min(i + 2, last), i3 = min(i + 3, last);
    int e1 = __builtin_nontemporal_load(dst_event + i1);
    int e2 = __builtin_nontemporal_load(dst_event + i2);
    int e3 = __builtin_nontemporal_load(dst_event + i3);
    int n0 = __builtin_nontemporal_load(dst_node + i);
    int n1 = __builtin_nontemporal_load(dst_node + i1);
    int n2 = __builtin_nontemporal_load(dst_node + i2);
    int n3 = __builtin_nontemporal_load(dst_node + i3);
    // issue all gathers in parallel (clamped indices are always valid)
    float v0 = __half2float(nm16[n0]);
    float v1 = __half2float(nm16[n1]);
    float v2 = __half2float(nm16[n2]);
    float v3 = __half2float(nm16[n3]);
    float vs = __half2float(nm16[__builtin_nontemporal_load(event_src + e)]);
    bool c1 = (i1 > i) && (e1 == e);
    bool c2 = c1 && (i2 > i1) && (e2 == e);
    bool c3 = c2 && (i3 > i2) && (e3 == e);
    float dsum = v0 + (c1 ? v1 : 0.0f) + (c2 ? v2 : 0.0f) + (c3 ? v3 : 0.0f);
    int nd = 1 + (int)c1 + (int)c2 + (int)c3;
    float t = vs + dsum / (float)(nd + 1);
    int p = __builtin_nontemporal_load(event_pair + e);
    unsigned* dst = pair_acc + (size_t)(blockIdx.x & (NXCD - 1)) * n_pairs + p;
    atomicAdd(dst, pack1_32(t));
}

// Combine 8 pair_acc replicas (fields add linearly), compute pair mean,
// accumulate into place_acc. nm[pair_place] hoisted here (f32 table).
__global__ void pair_k(const unsigned* __restrict__ pair_acc,
                       const int* __restrict__ pair_place,
                       const float* __restrict__ node_mean,
                       unsigned long long* __restrict__ place_acc, int n_pairs) {
    int p = blockIdx.x * blockDim.x + threadIdx.x;
    if (p >= n_pairs) return;
    unsigned a = 0;
#pragma unroll
    for (int c = 0; c < NXCD; ++c)
        a += pair_acc[(size_t)c * n_pairs + p];
    int cnt; float tsum;
    unpack32(a, cnt, tsum);
    if (cnt > 0) {
        int pl = pair_place[p];
        float pm = node_mean[pl] * (1.0f / 3.0f) + tsum / (3.0f * (float)cnt);
        atomicAdd(&place_acc[pl], pack1_64(pm));
    }
}

// Broadcast place_mean across 3*EMB=1536 cols; nontemporal float4 stores.
__global__ void out_k(const unsigned long long* __restrict__ place_acc,
                      float* __restrict__ out, int n_float4) {
    constexpr int ROW_F4 = 3 * EMB / 4;           // 384 float4 per row
    int stride = gridDim.x * blockDim.x;
    for (int g = blockIdx.x * blockDim.x + threadIdx.x; g < n_float4; g += stride) {
        int row = (int)((unsigned)g / (unsigned)ROW_F4);
        int cnt; float psum;
        unpack64(place_acc[row], cnt, psum);
        float v = (cnt > 0) ? psum / (float)cnt : 0.0f;
        floatx4 val = {v, v, v, v};
        __builtin_nontemporal_store(val, (floatx4*)out + g);
    }
}

extern "C" void kernel_launch(void* const* d_in, const int* in_sizes, int n_in,
                              void* d_out, int out_size, void* d_ws, size_t ws_size,
                              hipStream_t stream) {
    const float* emb        = (const float*)d_in[0];
    const int*   pair_place = (const int*)d_in[1];
    const int*   event_pair = (const int*)d_in[2];
    const int*   event_src  = (const int*)d_in[3];
    const int*   dst_event  = (const int*)d_in[5];
    const int*   dst_node   = (const int*)d_in[6];

    const int n_nodes  = in_sizes[0] / EMB;
    const int n_pairs  = in_sizes[1];
    const int n_dst    = in_sizes[5];

    // workspace: node_mean f32 (64 KB) | nm16 (32 KB) | pair_acc u32 x8
    //            (6.4 MB) | place_acc u64 (128 KB).
    // place_acc offset = 98304 + 8*n_pairs*4 = 98304 + 6400000 = 6498304,
    // divisible by 8. ok.
    char* base = (char*)d_ws;
    float* node_mean = (float*)base;
    __half* nm16 = (__half*)(base + (size_t)n_nodes * 4);
    unsigned* pair_acc = (unsigned*)(base + (size_t)n_nodes * 6);
    unsigned long long* place_acc =
        (unsigned long long*)(base + (size_t)n_nodes * 6 +
                              (size_t)NXCD * n_pairs * 4);

    (void)hipMemsetAsync(pair_acc, 0,
                         (size_t)NXCD * n_pairs * 4 + (size_t)n_nodes * 8, stream);

    node_mean_k<<<(n_nodes + 3) / 4, 256, 0, stream>>>(emb, node_mean, nm16, n_nodes);
    event_fused_k<<<(n_dst + 255) / 256, 256, 0, stream>>>(
        dst_event, dst_node, event_pair, event_src, nm16, pair_acc,
        n_dst, n_pairs);
    pair_k<<<(n_pairs + 255) / 256, 256, 0, stream>>>(
        pair_acc, pair_place, node_mean, place_acc, n_pairs);
    const int n_float4 = n_nodes * (3 * EMB / 4);
    out_k<<<4096, 256, 0, stream>>>(place_acc, (float*)d_out, n_float4);
}